// Round 5
// baseline (415.621 us; speedup 1.0000x reference)
//
#include <hip/hip_runtime.h>
#include <math.h>

// CTC batch cost: B=256, T=256, C=1024, L=32 -> S=65 extended states.
// Round 5: barrier-free streaming selection.
//  K1: stream ALL of y_pred coalesced (268 MB @ ~6.5 TB/s); per-block LDS
//    class->slot byte map (1024 B) does the 33-of-1024 selection inline.
//    No barriers in the stream loop, 4096 blocks -> loads always in flight.
//    Hits (~3% of elements) take __logf + scattered 4B store into compact
//    ws[b][t][33]. Duplicate labels: map keeps first occurrence only.
//  K2: 1 wave per batch element; rep[] (first occurrence of each label)
//    via 32-shfl scan; depth-16 register prefetch pipeline; alpha states
//    in registers (lane i holds states 2i, 2i+1).

#define Bt 256
#define Tt 256
#define Ct 1024
#define Lt 32
#define NSEL 33
#define RPB 16              // rows per block (chunk)
#define NEGV (-1e30f)
#define EPSV (1e-7f)

__device__ __forceinline__ float lae2(float a, float b) {
    float m = fmaxf(a, b);
    return m + __logf(__expf(a - m) + __expf(b - m));
}
__device__ __forceinline__ float lae3(float a, float b, float c) {
    float m = fmaxf(fmaxf(a, b), c);
    return m + __logf(__expf(a - m) + __expf(b - m) + __expf(c - m));
}

// ---- K1: streaming selection ----
__global__ __launch_bounds__(256) void ctc_sel(const int* __restrict__ y_true,
                                               const float* __restrict__ y_pred,
                                               float* __restrict__ ws) {
    __shared__ unsigned char map[Ct];          // class -> slot (0..32) or 0xFF
    const int tid = threadIdx.x;
    const int b = blockIdx.x >> 4;
    const int chunk = blockIdx.x & 15;

    ((unsigned*)map)[tid] = 0xFFFFFFFFu;
    __syncthreads();
    if (tid == 0) {
        map[Ct - 1] = 32;                      // blank
        const int* lab = y_true + b * Lt;
        for (int j = Lt - 1; j >= 0; --j)      // descending: smallest j wins
            map[lab[j]] = (unsigned char)j;
    }
    __syncthreads();

    const float4* src = (const float4*)y_pred
                      + ((size_t)b * Tt * Ct + (size_t)chunk * RPB * Ct) / 4;
    float* wsb = ws + ((size_t)b * Tt + (size_t)chunk * RPB) * NSEL;

    #pragma unroll
    for (int i = 0; i < 16; ++i) {
        int f = i * 256 + tid;                 // float4 index within chunk
        float4 v = src[f];
        int row = f >> 8;                      // row (timestep) within chunk
        int cbase = (f & 255) << 2;            // class base for this float4
        unsigned m4 = *(const unsigned*)(map + cbase);   // 4 map bytes, aligned
        if (m4 != 0xFFFFFFFFu) {
            float* wr = wsb + row * NSEL;
            unsigned m0 = m4 & 255u, m1 = (m4 >> 8) & 255u;
            unsigned m2 = (m4 >> 16) & 255u, m3 = m4 >> 24;
            if (m0 != 255u) wr[m0] = __logf(v.x + EPSV);
            if (m1 != 255u) wr[m1] = __logf(v.y + EPSV);
            if (m2 != 255u) wr[m2] = __logf(v.z + EPSV);
            if (m3 != 255u) wr[m3] = __logf(v.w + EPSV);
        }
    }
}

// ---- K2: serial alpha recursion per batch element ----
__global__ __launch_bounds__(64) void ctc_rec(const int* __restrict__ y_true,
                                              const float* __restrict__ ws,
                                              float* __restrict__ out) {
    const int b = blockIdx.x;
    const int lane = threadIdx.x;
    const float* lp = ws + (size_t)b * Tt * NSEL;
    const int* lab = y_true + b * Lt;

    int cls = (lane < 32) ? lab[lane] : (Ct - 1);
    // rep = first lane (<=lane) holding the same class (K1 wrote only that slot)
    int rep = lane;
    for (int k = 0; k < 32; ++k) {
        int ck = __shfl(cls, k);
        if (k < lane && ck == cls && k < rep) rep = k;
    }
    const int li = (lane < 32) ? rep : 32;

    bool allow = true;
    if (lane >= 1 && lane < 32) {
        int lprev = __shfl(cls, lane - 1);
        allow = (cls != Ct - 1) && (cls != lprev);
    }
    unsigned long long nz = __ballot(lane < 32 && cls != 0);
    int ll = (int)__popcll(nz);

    float buf[16];
    #pragma unroll
    for (int k = 0; k < 16; ++k) buf[k] = lp[k * NSEL + li];

    float a_even = NEGV, a_odd = NEGV;
    for (int g = 0; g < 16; ++g) {
        #pragma unroll
        for (int k = 0; k < 16; ++k) {
            float cur = buf[k];
            // refill with t+16; final group's refill lands past this b's
            // region (still inside the ~1GB ws) and is never consumed.
            buf[k] = lp[((unsigned)((g + 1) * 16 + k)) * NSEL + li];
            float le = __shfl(cur, 32);                 // blank, broadcast
            float lo = (lane < 32) ? cur : NEGV;        // label log-prob
            if (k == 0 && g == 0) {
                a_even = (lane == 0) ? le : NEGV;
                a_odd  = (lane == 0) ? lo : NEGV;
            } else {
                float po = __shfl_up(a_odd, 1);         // old a[2i-1]
                if (lane == 0) po = NEGV;
                float ne = le + lae2(a_even, po);
                float no = lo + lae3(a_odd, a_even, allow ? po : NEGV);
                a_even = ne;
                a_odd  = no;
            }
        }
    }

    float v1 = __shfl(a_even, ll);                       // alpha[2*ll]
    float v2 = (ll >= 1) ? __shfl(a_odd, ll - 1) : NEGV; // alpha[2*ll-1]
    if (lane == 0) out[b] = -lae2(v1, v2);
}

extern "C" void kernel_launch(void* const* d_in, const int* in_sizes, int n_in,
                              void* d_out, int out_size, void* d_ws, size_t ws_size,
                              hipStream_t stream) {
    const int* y_true = (const int*)d_in[0];
    const float* y_pred = (const float*)d_in[1];
    float* out = (float*)d_out;
    float* ws = (float*)d_ws;
    (void)in_sizes; (void)n_in; (void)out_size; (void)ws_size;
    ctc_sel<<<Bt * (Tt / RPB), 256, 0, stream>>>(y_true, y_pred, ws);
    ctc_rec<<<Bt, 64, 0, stream>>>(y_true, ws, out);
}